// Round 1
// baseline (562.766 us; speedup 1.0000x reference)
//
#include <hip/hip_runtime.h>

#define NV 6890
#define NJ 24
#define BATCH 512
#define KP 207    // pose-blend K (207 = 23*9)
#define KPP 208   // padded K
#define VT 64     // verts per block tile
#define BT 16     // batches per block tile
#define KC 52     // K chunk staged in LDS
#define NCHUNK 4  // 4*52 = 208

// ws layout (float offsets)
#define WS_LROT 0
#define WS_A    (BATCH * KPP)            // 106496: A matrices [B][24][12]
#define WS_JS   (WS_A + BATCH * NJ * 12) // 253952: per-joint [24][33] = {Jt[3], JS[3][10]}

typedef float f4 __attribute__((ext_vector_type(4)));

// ---------------- K0: JS = Jreg*shapedirs, Jt = Jreg*v_template ----------------
__global__ void k_jreg(const float* __restrict__ Jreg, const float* __restrict__ vtemp,
                       const float* __restrict__ sdirs, float* __restrict__ ws) {
  int j = blockIdx.x;
  int tid = threadIdx.x;
  float acc[33];
#pragma unroll
  for (int i = 0; i < 33; ++i) acc[i] = 0.f;
  for (int v = tid; v < NV; v += 256) {
    float w = Jreg[j * NV + v];
#pragma unroll
    for (int c = 0; c < 3; ++c) {
      acc[c] += w * vtemp[v * 3 + c];
#pragma unroll
      for (int t = 0; t < 10; ++t)
        acc[3 + c * 10 + t] += w * sdirs[v * 30 + c * 10 + t];
    }
  }
  __shared__ float red[256];
  float* out = ws + WS_JS + j * 33;
  for (int i = 0; i < 33; ++i) {
    red[tid] = acc[i];
    __syncthreads();
    for (int s = 128; s > 0; s >>= 1) {
      if (tid < s) red[tid] += red[tid + s];
      __syncthreads();
    }
    if (tid == 0) out[i] = red[0];
    __syncthreads();
  }
}

// ---------------- K1: per-batch joints, rodrigues, chain, A matrices ----------------
__global__ void k_batch(const float* __restrict__ pose, const float* __restrict__ beta,
                        const int* __restrict__ parent, float* __restrict__ ws) {
  int b = blockIdx.x;
  int j = threadIdx.x;  // 64 threads; j<24 active
  __shared__ float jl[NJ][3];   // J[b][j][c]
  __shared__ float gl[NJ][16];  // G_local 3x4 rows (pad 16 for banks)

  float bt[10];
#pragma unroll
  for (int t = 0; t < 10; ++t) bt[t] = beta[b * 10 + t];

  float R[9];
  float Jj[3] = {0.f, 0.f, 0.f};
  if (j < NJ) {
    const float* js = ws + WS_JS + j * 33;
#pragma unroll
    for (int c = 0; c < 3; ++c) {
      float a = js[c];
#pragma unroll
      for (int t = 0; t < 10; ++t) a += js[3 + c * 10 + t] * bt[t];
      Jj[c] = a;
      jl[j][c] = a;
    }
    float rx = pose[b * 72 + j * 3 + 0];
    float ry = pose[b * 72 + j * 3 + 1];
    float rz = pose[b * 72 + j * 3 + 2];
    float theta = sqrtf(rx * rx + ry * ry + rz * rz) + 1e-8f;
    float inv = 1.f / theta;
    float ax = rx * inv, ay = ry * inv, az = rz * inv;
    float c = cosf(theta), s = sinf(theta), oc = 1.f - c;
    R[0] = c + oc * ax * ax;      R[1] = oc * ax * ay - s * az; R[2] = oc * ax * az + s * ay;
    R[3] = oc * ax * ay + s * az; R[4] = c + oc * ay * ay;      R[5] = oc * ay * az - s * ax;
    R[6] = oc * ax * az - s * ay; R[7] = oc * ay * az + s * ax; R[8] = c + oc * az * az;
  }
  __syncthreads();

  if (j >= 1 && j < NJ) {
    float* lr = ws + WS_LROT + b * KPP + (j - 1) * 9;
#pragma unroll
    for (int k = 0; k < 9; ++k)
      lr[k] = R[k] - ((k == 0 || k == 4 || k == 8) ? 1.f : 0.f);
  }
  if (j == 0) ws[WS_LROT + b * KPP + 207] = 0.f;  // K padding

  if (j < NJ) {
    int par = (j == 0) ? 0 : parent[j - 1];
#pragma unroll
    for (int r = 0; r < 3; ++r) {
      gl[j][r * 4 + 0] = R[r * 3 + 0];
      gl[j][r * 4 + 1] = R[r * 3 + 1];
      gl[j][r * 4 + 2] = R[r * 3 + 2];
      gl[j][r * 4 + 3] = (j == 0) ? Jj[r] : Jj[r] - jl[par][r];
    }
  }
  __syncthreads();

  if (j < NJ) {
    // ancestor walk: chain root->j, same associativity as reference
    int a[12];
    int n = 0, cur = j;
    while (cur != 0 && n < 12) { a[n++] = cur; cur = parent[cur - 1]; }
    float G[12];
#pragma unroll
    for (int r = 0; r < 3; ++r)
      for (int cc = 0; cc < 4; ++cc) G[r * 4 + cc] = gl[0][r * 4 + cc];
    for (int i = n - 1; i >= 0; --i) {
      const float* L = gl[a[i]];
      float C[12];
#pragma unroll
      for (int r = 0; r < 3; ++r) {
#pragma unroll
        for (int cc = 0; cc < 4; ++cc) {
          float sacc = (cc == 3) ? G[r * 4 + 3] : 0.f;
#pragma unroll
          for (int k = 0; k < 3; ++k) sacc += G[r * 4 + k] * L[k * 4 + cc];
          C[r * 4 + cc] = sacc;
        }
      }
#pragma unroll
      for (int k = 0; k < 12; ++k) G[k] = C[k];
    }
    // rest subtraction: only last column changes
    float* A = ws + WS_A + b * NJ * 12 + j * 12;
#pragma unroll
    for (int r = 0; r < 3; ++r) {
      A[r * 4 + 0] = G[r * 4 + 0];
      A[r * 4 + 1] = G[r * 4 + 1];
      A[r * 4 + 2] = G[r * 4 + 2];
      A[r * 4 + 3] = G[r * 4 + 3] -
                     (G[r * 4 + 0] * jl[j][0] + G[r * 4 + 1] * jl[j][1] + G[r * 4 + 2] * jl[j][2]);
    }
  }
}

// ---------------- K2: fused shape blend + pose blend GEMM + skinning ----------------
#define PD_ROWB 640  // bytes per vert row in LDS (160 floats, 156 used)

__launch_bounds__(256)
__global__ void k_main(const float* __restrict__ beta, const float* __restrict__ vtemp,
                       const float* __restrict__ sdirs, const float* __restrict__ pdirs,
                       const float* __restrict__ wgt, const float* __restrict__ ws,
                       float* __restrict__ out) {
  __shared__ union {
    float pd[VT * 160];                              // 40960 B, XOR-swizzled
    struct { float A[BT * 288]; float w[VT * 25]; } skin;  // 24832 B
  } u;
  __shared__ float lrot[BT * KPP];  // 13312 B
  __shared__ float sd[VT * 30];     // 7680 B
  __shared__ float btl[BT * 10];
  __shared__ float vtl[VT * 3];

  int tid = threadIdx.x;
  int vt0 = blockIdx.x * VT;
  int b0 = blockIdx.y * BT;
  int tv = tid & 63;   // vert within tile; whole wave shares bg -> broadcast lrot/A reads
  int bg = tid >> 6;   // batch group 0..3 (4 batches each)
  int vg = vt0 + tv;
  bool vok = vg < NV;

  // stage lrot tile (float4), beta, shapedirs, v_template
  {
    const f4* src = (const f4*)(ws + WS_LROT);
    f4* dst = (f4*)lrot;
    for (int i = tid; i < BT * 52; i += 256) {
      int b = i / 52, q = i % 52;
      dst[b * 52 + q] = src[(size_t)(b0 + b) * 52 + q];
    }
  }
  for (int i = tid; i < BT * 10; i += 256) btl[i] = beta[b0 * 10 + i];
  for (int i = tid; i < VT * 30; i += 256) {
    int v = i / 30;
    sd[i] = (vt0 + v < NV) ? sdirs[(size_t)(vt0 + v) * 30 + (i % 30)] : 0.f;
  }
  for (int i = tid; i < VT * 3; i += 256) {
    int v = i / 3;
    vtl[i] = (vt0 + v < NV) ? vtemp[(size_t)vt0 * 3 + i] : 0.f;
  }
  __syncthreads();

  // acc init: v_template + shapedirs*beta
  float acc[4][3];
#pragma unroll
  for (int k = 0; k < 4; ++k) {
    int bl = bg * 4 + k;
#pragma unroll
    for (int c = 0; c < 3; ++c) {
      float a = vtl[tv * 3 + c];
#pragma unroll
      for (int t = 0; t < 10; ++t) a += sd[tv * 30 + c * 10 + t] * btl[bl * 10 + t];
      acc[k][c] = a;
    }
  }

  // pose blend GEMM: acc[k][c] += sum_p pd[v][c][p] * lrot[b][p]
  char* pdb = (char*)u.pd;
  for (int ch = 0; ch < NCHUNK; ++ch) {
    __syncthreads();  // protect pd buffer reuse
    int pb = ch * KC;
    for (int i = tid; i < VT * 156; i += 256) {
      int v = i / 156, r = i % 156;
      int c = r / 52, pl = r % 52;
      int gp = pb + pl;
      int vv = vt0 + v;
      float val = (vv < NV && gp < KP) ? pdirs[(size_t)vv * 621 + c * 207 + gp] : 0.f;
      int byte = v * PD_ROWB + (c * 52 + pl) * 4;
      *(float*)(pdb + (byte ^ ((v & 7) << 4))) = val;
    }
    __syncthreads();
    const f4* lr4 = (const f4*)lrot;
#pragma unroll
    for (int q = 0; q < KC / 4; ++q) {
      f4 p0 = *(const f4*)(pdb + ((tv * PD_ROWB + (0 * 52 + q * 4) * 4) ^ ((tv & 7) << 4)));
      f4 p1 = *(const f4*)(pdb + ((tv * PD_ROWB + (1 * 52 + q * 4) * 4) ^ ((tv & 7) << 4)));
      f4 p2 = *(const f4*)(pdb + ((tv * PD_ROWB + (2 * 52 + q * 4) * 4) ^ ((tv & 7) << 4)));
#pragma unroll
      for (int k = 0; k < 4; ++k) {
        f4 l = lr4[(bg * 4 + k) * 52 + ch * 13 + q];
#pragma unroll
        for (int e = 0; e < 4; ++e) {
          acc[k][0] += p0[e] * l[e];
          acc[k][1] += p1[e] * l[e];
          acc[k][2] += p2[e] * l[e];
        }
      }
    }
  }

  // skinning: v_out = sum_j w[v][j] * (A[b][j] . [v_posed,1])
  __syncthreads();
  {
    const f4* srcA = (const f4*)(ws + WS_A);
    f4* dstA = (f4*)u.skin.A;
    for (int i = tid; i < BT * 72; i += 256) {
      int b = i / 72, q = i % 72;
      dstA[b * 72 + q] = srcA[(size_t)(b0 + b) * 72 + q];
    }
    for (int i = tid; i < VT * 24; i += 256) {
      int v = i / 24, q = i % 24;
      u.skin.w[v * 25 + q] = (vt0 + v < NV) ? wgt[(size_t)(vt0 + v) * 24 + q] : 0.f;
    }
  }
  __syncthreads();

  float vout[4][3];
#pragma unroll
  for (int k = 0; k < 4; ++k)
#pragma unroll
    for (int c = 0; c < 3; ++c) vout[k][c] = 0.f;

  const f4* A4 = (const f4*)u.skin.A;
#pragma unroll 4
  for (int j = 0; j < NJ; ++j) {
    float w = u.skin.w[tv * 25 + j];
#pragma unroll
    for (int k = 0; k < 4; ++k) {
      int bl = bg * 4 + k;
      f4 a0 = A4[bl * 72 + j * 3 + 0];
      f4 a1 = A4[bl * 72 + j * 3 + 1];
      f4 a2 = A4[bl * 72 + j * 3 + 2];
      float sx = a0.x * acc[k][0] + a0.y * acc[k][1] + a0.z * acc[k][2] + a0.w;
      float sy = a1.x * acc[k][0] + a1.y * acc[k][1] + a1.z * acc[k][2] + a1.w;
      float sz = a2.x * acc[k][0] + a2.y * acc[k][1] + a2.z * acc[k][2] + a2.w;
      vout[k][0] += w * sx;
      vout[k][1] += w * sy;
      vout[k][2] += w * sz;
    }
  }

  if (vok) {
#pragma unroll
    for (int k = 0; k < 4; ++k) {
      int bl = b0 + bg * 4 + k;
      float* o = out + ((size_t)bl * NV + vg) * 3;
      o[0] = vout[k][0];
      o[1] = vout[k][1];
      o[2] = vout[k][2];
    }
  }
}

extern "C" void kernel_launch(void* const* d_in, const int* in_sizes, int n_in,
                              void* d_out, int out_size, void* d_ws, size_t ws_size,
                              hipStream_t stream) {
  const float* pose   = (const float*)d_in[0];
  const float* beta   = (const float*)d_in[1];
  const float* vtemp  = (const float*)d_in[2];
  const float* sdirs  = (const float*)d_in[3];
  const float* pdirs  = (const float*)d_in[4];
  const float* Jreg   = (const float*)d_in[5];
  const float* wgt    = (const float*)d_in[6];
  const int*   parent = (const int*)d_in[7];
  float* ws  = (float*)d_ws;
  float* out = (float*)d_out;

  hipLaunchKernelGGL(k_jreg, dim3(NJ), dim3(256), 0, stream, Jreg, vtemp, sdirs, ws);
  hipLaunchKernelGGL(k_batch, dim3(BATCH), dim3(64), 0, stream, pose, beta, parent, ws);
  dim3 grid((NV + VT - 1) / VT, BATCH / BT);
  hipLaunchKernelGGL(k_main, grid, dim3(256), 0, stream, beta, vtemp, sdirs, pdirs, wgt, ws, out);
}

// Round 2
// 166.024 us; speedup vs baseline: 3.3897x; 3.3897x over previous
//
#include <hip/hip_runtime.h>

#define NV 6890
#define NJ 24
#define BATCH 512
#define NCOL 20670   // NV*3
#define NCOLP 20736  // padded to 128
#define KK 224       // 207 padded to 7*32
#define VT 64
#define BT 16

typedef float f4 __attribute__((ext_vector_type(4)));
typedef float f32x4 __attribute__((ext_vector_type(4)));
typedef short bf16x8 __attribute__((ext_vector_type(8)));
typedef unsigned short ushort8 __attribute__((ext_vector_type(8)));

// ws layout:
//   Abuf  ushort[512][224]          @ 0        (229376 B)
//   Bbuf  ushort[20736][224]        @ 229376   (9289728 B)
//   Amat  float[512][24][12]        @ 9519104  (589824 B)
//   JS    float[24][33]             @ 10108928 (3168 B)

__device__ __forceinline__ ushort bf16_rne(float x) {
  union { float f; unsigned u; } c; c.f = x;
  unsigned r = c.u + 0x7fffu + ((c.u >> 16) & 1u);
  return (ushort)(r >> 16);
}

// ---------------- K0: JS = Jreg*shapedirs, Jt = Jreg*v_template ----------------
__global__ void k_jreg(const float* __restrict__ Jreg, const float* __restrict__ vtemp,
                       const float* __restrict__ sdirs, float* __restrict__ JSp) {
  int j = blockIdx.x;
  int tid = threadIdx.x;
  float acc[33];
#pragma unroll
  for (int i = 0; i < 33; ++i) acc[i] = 0.f;
  for (int v = tid; v < NV; v += 256) {
    float w = Jreg[j * NV + v];
#pragma unroll
    for (int c = 0; c < 3; ++c) {
      acc[c] += w * vtemp[v * 3 + c];
#pragma unroll
      for (int t = 0; t < 10; ++t)
        acc[3 + c * 10 + t] += w * sdirs[v * 30 + c * 10 + t];
    }
  }
  __shared__ float red[256];
  float* out = JSp + j * 33;
  for (int i = 0; i < 33; ++i) {
    red[tid] = acc[i];
    __syncthreads();
    for (int s = 128; s > 0; s >>= 1) {
      if (tid < s) red[tid] += red[tid + s];
      __syncthreads();
    }
    if (tid == 0) out[i] = red[0];
    __syncthreads();
  }
}

// ---------------- K1: per-batch joints, rodrigues, chain, A matrices, Abuf ----------------
__global__ void k_batch(const float* __restrict__ pose, const float* __restrict__ beta,
                        const int* __restrict__ parent, const float* __restrict__ JSp,
                        ushort* __restrict__ Abuf, float* __restrict__ Amat) {
  int b = blockIdx.x;
  int j = threadIdx.x;  // 64 threads; j<24 active mostly
  __shared__ float jl[NJ][3];
  __shared__ float gl[NJ][16];

  float bt[10];
#pragma unroll
  for (int t = 0; t < 10; ++t) bt[t] = beta[b * 10 + t];

  float R[9];
  float Jj[3] = {0.f, 0.f, 0.f};
  if (j < NJ) {
    const float* js = JSp + j * 33;
#pragma unroll
    for (int c = 0; c < 3; ++c) {
      float a = js[c];
#pragma unroll
      for (int t = 0; t < 10; ++t) a += js[3 + c * 10 + t] * bt[t];
      Jj[c] = a;
      jl[j][c] = a;
    }
    float rx = pose[b * 72 + j * 3 + 0];
    float ry = pose[b * 72 + j * 3 + 1];
    float rz = pose[b * 72 + j * 3 + 2];
    float theta = sqrtf(rx * rx + ry * ry + rz * rz) + 1e-8f;
    float inv = 1.f / theta;
    float ax = rx * inv, ay = ry * inv, az = rz * inv;
    float c = cosf(theta), s = sinf(theta), oc = 1.f - c;
    R[0] = c + oc * ax * ax;      R[1] = oc * ax * ay - s * az; R[2] = oc * ax * az + s * ay;
    R[3] = oc * ax * ay + s * az; R[4] = c + oc * ay * ay;      R[5] = oc * ay * az - s * ax;
    R[6] = oc * ax * az - s * ay; R[7] = oc * ay * az + s * ax; R[8] = c + oc * az * az;
  }
  __syncthreads();

  // lrotmin -> Abuf (bf16), cols 0..206; pad 207..223 with zeros
  if (j >= 1 && j < NJ) {
    ushort* lr = Abuf + b * KK + (j - 1) * 9;
#pragma unroll
    for (int k = 0; k < 9; ++k)
      lr[k] = bf16_rne(R[k] - ((k == 0 || k == 4 || k == 8) ? 1.f : 0.f));
  }
  if (j >= 32 && j < 49) Abuf[b * KK + 175 + j] = 0;  // k = 207..223

  if (j < NJ) {
    int par = (j == 0) ? 0 : parent[j - 1];
#pragma unroll
    for (int r = 0; r < 3; ++r) {
      gl[j][r * 4 + 0] = R[r * 3 + 0];
      gl[j][r * 4 + 1] = R[r * 3 + 1];
      gl[j][r * 4 + 2] = R[r * 3 + 2];
      gl[j][r * 4 + 3] = (j == 0) ? Jj[r] : Jj[r] - jl[par][r];
    }
  }
  __syncthreads();

  if (j < NJ) {
    int a[12];
    int n = 0, cur = j;
    while (cur != 0 && n < 12) { a[n++] = cur; cur = parent[cur - 1]; }
    float G[12];
#pragma unroll
    for (int r = 0; r < 3; ++r)
#pragma unroll
      for (int cc = 0; cc < 4; ++cc) G[r * 4 + cc] = gl[0][r * 4 + cc];
    for (int i = n - 1; i >= 0; --i) {
      const float* L = gl[a[i]];
      float C[12];
#pragma unroll
      for (int r = 0; r < 3; ++r) {
#pragma unroll
        for (int cc = 0; cc < 4; ++cc) {
          float sacc = (cc == 3) ? G[r * 4 + 3] : 0.f;
#pragma unroll
          for (int k = 0; k < 3; ++k) sacc += G[r * 4 + k] * L[k * 4 + cc];
          C[r * 4 + cc] = sacc;
        }
      }
#pragma unroll
      for (int k = 0; k < 12; ++k) G[k] = C[k];
    }
    float* A = Amat + b * 288 + j * 12;
#pragma unroll
    for (int r = 0; r < 3; ++r) {
      A[r * 4 + 0] = G[r * 4 + 0];
      A[r * 4 + 1] = G[r * 4 + 1];
      A[r * 4 + 2] = G[r * 4 + 2];
      A[r * 4 + 3] = G[r * 4 + 3] -
                     (G[r * 4 + 0] * jl[j][0] + G[r * 4 + 1] * jl[j][1] + G[r * 4 + 2] * jl[j][2]);
    }
  }
}

// ---------------- K2: posedirs f32 -> Bbuf bf16 [20736][224] ----------------
__global__ void k_prepb(const float* __restrict__ pdirs, ushort* __restrict__ Bbuf) {
  int idx = blockIdx.x * 256 + threadIdx.x;  // 20736*28 = 580608 total
  int n = idx / 28, k8 = idx % 28;
  int kbase = k8 * 8;
  ushort8 o;
#pragma unroll
  for (int e = 0; e < 8; ++e) {
    int k = kbase + e;
    float v = (n < NCOL && k < 207) ? pdirs[(size_t)n * 207 + k] : 0.f;
    o[e] = bf16_rne(v);
  }
  *(ushort8*)(Bbuf + (size_t)n * KK + kbase) = o;
}

// ---------------- K3: MFMA GEMM  vp[b][n] = sum_k Abuf[b][k]*Bbuf[n][k] ----------------
// grid (162, 8): block = 4 waves, each wave: 32 cols (2 strips of 16) x 64 batches
__launch_bounds__(256)
__global__ void k_gemm(const ushort* __restrict__ Abuf, const ushort* __restrict__ Bbuf,
                       float* __restrict__ out) {
  int tid = threadIdx.x;
  int wid = tid >> 6, lane = tid & 63;
  int lo = lane & 15, hi = lane >> 4;  // 0..3
  int n0 = blockIdx.x * 128 + wid * 32;
  int m0b = blockIdx.y * 64;

  bf16x8 Bf[2][7];
#pragma unroll
  for (int s = 0; s < 2; ++s) {
    const ushort* brow = Bbuf + (size_t)(n0 + s * 16 + lo) * KK + hi * 8;
#pragma unroll
    for (int kc = 0; kc < 7; ++kc)
      Bf[s][kc] = *(const bf16x8*)(brow + kc * 32);
  }

#pragma unroll
  for (int mt = 0; mt < 4; ++mt) {
    int m0 = m0b + mt * 16;
    const ushort* arow = Abuf + (size_t)(m0 + lo) * KK + hi * 8;
    f32x4 acc0 = {0.f, 0.f, 0.f, 0.f};
    f32x4 acc1 = {0.f, 0.f, 0.f, 0.f};
#pragma unroll
    for (int kc = 0; kc < 7; ++kc) {
      bf16x8 Af = *(const bf16x8*)(arow + kc * 32);
      acc0 = __builtin_amdgcn_mfma_f32_16x16x32_bf16(Af, Bf[0][kc], acc0, 0, 0, 0);
      acc1 = __builtin_amdgcn_mfma_f32_16x16x32_bf16(Af, Bf[1][kc], acc1, 0, 0, 0);
    }
    int col0 = n0 + lo;
    if (col0 < NCOL) {
#pragma unroll
      for (int r = 0; r < 4; ++r)
        out[(size_t)(m0 + hi * 4 + r) * NCOL + col0] = acc0[r];
    }
    int col1 = n0 + 16 + lo;
    if (col1 < NCOL) {
#pragma unroll
      for (int r = 0; r < 4; ++r)
        out[(size_t)(m0 + hi * 4 + r) * NCOL + col1] = acc1[r];
    }
  }
}

// ---------------- K4: skinning in place on d_out ----------------
__launch_bounds__(256)
__global__ void k_skin(const float* __restrict__ beta, const float* __restrict__ vtemp,
                       const float* __restrict__ sdirs, const float* __restrict__ wgt,
                       const float* __restrict__ Amat, float* __restrict__ out) {
  __shared__ float Al[BT * 288];  // 18432 B
  __shared__ float wl[VT * 25];   // 6400 B
  __shared__ float sd[VT * 30];   // 7680 B
  __shared__ float btl[BT * 10];
  __shared__ float vtl[VT * 3];

  int tid = threadIdx.x;
  int vt0 = blockIdx.x * VT, b0 = blockIdx.y * BT;
  int tv = tid & 63, bg = tid >> 6;
  int vg = vt0 + tv;
  bool vok = vg < NV;

  {
    const f4* srcA = (const f4*)(Amat + (size_t)b0 * 288);
    f4* dstA = (f4*)Al;
    for (int i = tid; i < BT * 72; i += 256) dstA[i] = srcA[i];
  }
  for (int i = tid; i < VT * 24; i += 256) {
    int v = i / 24, q = i % 24;
    wl[v * 25 + q] = (vt0 + v < NV) ? wgt[(size_t)(vt0 + v) * 24 + q] : 0.f;
  }
  for (int i = tid; i < BT * 10; i += 256) btl[i] = beta[b0 * 10 + i];
  for (int i = tid; i < VT * 30; i += 256) {
    int v = i / 30;
    sd[i] = (vt0 + v < NV) ? sdirs[(size_t)(vt0 + v) * 30 + (i % 30)] : 0.f;
  }
  for (int i = tid; i < VT * 3; i += 256)
    vtl[i] = (vt0 * 3 + i < NV * 3) ? vtemp[(size_t)vt0 * 3 + i] : 0.f;
  __syncthreads();

  // v_posed = (pose blend from out) + v_template + shapedirs*beta
  float vp[4][3];
#pragma unroll
  for (int k = 0; k < 4; ++k) {
    int bl = b0 + bg * 4 + k;
    const float* ip = out + ((size_t)bl * NV + vg) * 3;
    float p[3] = {0.f, 0.f, 0.f};
    if (vok) { p[0] = ip[0]; p[1] = ip[1]; p[2] = ip[2]; }
#pragma unroll
    for (int c = 0; c < 3; ++c) {
      float a = vtl[tv * 3 + c];
#pragma unroll
      for (int t = 0; t < 10; ++t) a += sd[tv * 30 + c * 10 + t] * btl[(bg * 4 + k) * 10 + t];
      vp[k][c] = a + p[c];
    }
  }

  float vout[4][3];
#pragma unroll
  for (int k = 0; k < 4; ++k)
#pragma unroll
    for (int c = 0; c < 3; ++c) vout[k][c] = 0.f;

  const f4* A4 = (const f4*)Al;
#pragma unroll 4
  for (int j = 0; j < NJ; ++j) {
    float w = wl[tv * 25 + j];
#pragma unroll
    for (int k = 0; k < 4; ++k) {
      int bl = bg * 4 + k;
      f4 a0 = A4[bl * 72 + j * 3 + 0];
      f4 a1 = A4[bl * 72 + j * 3 + 1];
      f4 a2 = A4[bl * 72 + j * 3 + 2];
      float sx = a0.x * vp[k][0] + a0.y * vp[k][1] + a0.z * vp[k][2] + a0.w;
      float sy = a1.x * vp[k][0] + a1.y * vp[k][1] + a1.z * vp[k][2] + a1.w;
      float sz = a2.x * vp[k][0] + a2.y * vp[k][1] + a2.z * vp[k][2] + a2.w;
      vout[k][0] += w * sx;
      vout[k][1] += w * sy;
      vout[k][2] += w * sz;
    }
  }

  if (vok) {
#pragma unroll
    for (int k = 0; k < 4; ++k) {
      int bl = b0 + bg * 4 + k;
      float* o = out + ((size_t)bl * NV + vg) * 3;
      o[0] = vout[k][0];
      o[1] = vout[k][1];
      o[2] = vout[k][2];
    }
  }
}

extern "C" void kernel_launch(void* const* d_in, const int* in_sizes, int n_in,
                              void* d_out, int out_size, void* d_ws, size_t ws_size,
                              hipStream_t stream) {
  const float* pose   = (const float*)d_in[0];
  const float* beta   = (const float*)d_in[1];
  const float* vtemp  = (const float*)d_in[2];
  const float* sdirs  = (const float*)d_in[3];
  const float* pdirs  = (const float*)d_in[4];
  const float* Jreg   = (const float*)d_in[5];
  const float* wgt    = (const float*)d_in[6];
  const int*   parent = (const int*)d_in[7];
  float* out = (float*)d_out;

  ushort* Abuf = (ushort*)d_ws;
  ushort* Bbuf = Abuf + (size_t)BATCH * KK;
  float*  Amat = (float*)(Bbuf + (size_t)NCOLP * KK);
  float*  JSp  = Amat + (size_t)BATCH * 288;

  hipLaunchKernelGGL(k_jreg, dim3(NJ), dim3(256), 0, stream, Jreg, vtemp, sdirs, JSp);
  hipLaunchKernelGGL(k_batch, dim3(BATCH), dim3(64), 0, stream, pose, beta, parent, JSp, Abuf, Amat);
  hipLaunchKernelGGL(k_prepb, dim3((NCOLP * 28) / 256), dim3(256), 0, stream, pdirs, Bbuf);
  hipLaunchKernelGGL(k_gemm, dim3(NCOLP / 128, 8), dim3(256), 0, stream, Abuf, Bbuf, out);
  dim3 grid((NV + VT - 1) / VT, BATCH / BT);
  hipLaunchKernelGGL(k_skin, grid, dim3(256), 0, stream, beta, vtemp, sdirs, wgt, Amat, out);
}

// Round 3
// 112.234 us; speedup vs baseline: 5.0142x; 1.4793x over previous
//
#include <hip/hip_runtime.h>

#define NV 6890
#define NJ 24
#define BATCH 512
#define NCOL 20670   // NV*3
#define NCOLP 20736  // padded to 128
#define KK 224       // 207 pose + 10 beta + 7 zero
#define VT 64
#define BT 16
#define JCH 864      // vert chunk for jreg stage A (8*864 >= 6890)

typedef float f4 __attribute__((ext_vector_type(4)));
typedef float f32x4 __attribute__((ext_vector_type(4)));
typedef short bf16x8 __attribute__((ext_vector_type(8)));
typedef unsigned short ushort8 __attribute__((ext_vector_type(8)));

// ws layout (bytes):
//   Abuf  ushort[512][224]     @ 0
//   Bbuf  ushort[20736][224]   @ 229376
//   Amat  float[512][24][12]   @ 9519104
//   JSp   float[24][33]        @ 10108928
//   part  float[24][8][33]     @ 10112096

__device__ __forceinline__ ushort bf16_rne(float x) {
  union { float f; unsigned u; } c; c.f = x;
  unsigned r = c.u + 0x7fffu + ((c.u >> 16) & 1u);
  return (ushort)(r >> 16);
}

// ---------------- K0a: partial JS reduction, grid (24, 8) ----------------
__global__ void k_jregA(const float* __restrict__ Jreg, const float* __restrict__ vtemp,
                        const float* __restrict__ sdirs, float* __restrict__ partial) {
  int j = blockIdx.x, bz = blockIdx.y;
  int tid = threadIdx.x;
  float acc[33];
#pragma unroll
  for (int i = 0; i < 33; ++i) acc[i] = 0.f;
  int v0 = bz * JCH;
  int v1 = v0 + JCH; if (v1 > NV) v1 = NV;
  for (int v = v0 + tid; v < v1; v += 256) {
    float w = Jreg[(size_t)j * NV + v];
    const float* vt = vtemp + (size_t)v * 3;
    acc[0] += w * vt[0]; acc[1] += w * vt[1]; acc[2] += w * vt[2];
    const float* sdv = sdirs + (size_t)v * 30;
#pragma unroll
    for (int t = 0; t < 30; ++t) acc[3 + t] += w * sdv[t];
  }
  // wave butterfly reduce (all lanes end with the sum)
#pragma unroll
  for (int i = 0; i < 33; ++i) {
    float a = acc[i];
#pragma unroll
    for (int s = 32; s > 0; s >>= 1) a += __shfl_xor(a, s, 64);
    acc[i] = a;
  }
  __shared__ float red[4][34];
  int lane = tid & 63, wv = tid >> 6;
  if (lane == 0) {
#pragma unroll
    for (int i = 0; i < 33; ++i) red[wv][i] = acc[i];
  }
  __syncthreads();
  if (tid < 33) {
    float s = red[0][tid] + red[1][tid] + red[2][tid] + red[3][tid];
    partial[((size_t)j * 8 + bz) * 33 + tid] = s;
  }
}

// ---------------- K0b: sum the 8 partials ----------------
__global__ void k_jregB(const float* __restrict__ partial, float* __restrict__ JSp) {
  int i = blockIdx.x * 256 + threadIdx.x;
  if (i < NJ * 33) {
    int j = i / 33, q = i % 33;
    float s = 0.f;
#pragma unroll
    for (int bz = 0; bz < 8; ++bz) s += partial[((size_t)j * 8 + bz) * 33 + q];
    JSp[i] = s;
  }
}

// ---------------- K1: per-batch joints, rodrigues, chain, A matrices, Abuf ----------------
__global__ void k_batch(const float* __restrict__ pose, const float* __restrict__ beta,
                        const int* __restrict__ parent, const float* __restrict__ JSp,
                        ushort* __restrict__ Abuf, float* __restrict__ Amat) {
  int b = blockIdx.x;
  int j = threadIdx.x;  // 64 threads
  __shared__ float jl[NJ][3];
  __shared__ float gl[NJ][16];

  float bt[10];
#pragma unroll
  for (int t = 0; t < 10; ++t) bt[t] = beta[b * 10 + t];

  float R[9];
  float Jj[3] = {0.f, 0.f, 0.f};
  if (j < NJ) {
    const float* js = JSp + j * 33;
#pragma unroll
    for (int c = 0; c < 3; ++c) {
      float a = js[c];
#pragma unroll
      for (int t = 0; t < 10; ++t) a += js[3 + c * 10 + t] * bt[t];
      Jj[c] = a;
      jl[j][c] = a;
    }
    float rx = pose[b * 72 + j * 3 + 0];
    float ry = pose[b * 72 + j * 3 + 1];
    float rz = pose[b * 72 + j * 3 + 2];
    float theta = sqrtf(rx * rx + ry * ry + rz * rz) + 1e-8f;
    float inv = 1.f / theta;
    float ax = rx * inv, ay = ry * inv, az = rz * inv;
    float c = cosf(theta), s = sinf(theta), oc = 1.f - c;
    R[0] = c + oc * ax * ax;      R[1] = oc * ax * ay - s * az; R[2] = oc * ax * az + s * ay;
    R[3] = oc * ax * ay + s * az; R[4] = c + oc * ay * ay;      R[5] = oc * ay * az - s * ax;
    R[6] = oc * ax * az - s * ay; R[7] = oc * ay * az + s * ax; R[8] = c + oc * az * az;
  }
  __syncthreads();

  // Abuf cols: 0..206 lrotmin, 207..216 beta, 217..223 zero (bf16)
  if (j >= 1 && j < NJ) {
    ushort* lr = Abuf + b * KK + (j - 1) * 9;
#pragma unroll
    for (int k = 0; k < 9; ++k)
      lr[k] = bf16_rne(R[k] - ((k == 0 || k == 4 || k == 8) ? 1.f : 0.f));
  }
  if (j >= 32 && j < 42) Abuf[b * KK + 207 + (j - 32)] = bf16_rne(bt[j - 32]);
  if (j >= 42 && j < 49) Abuf[b * KK + 207 + (j - 32)] = 0;

  if (j < NJ) {
    int par = (j == 0) ? 0 : parent[j - 1];
#pragma unroll
    for (int r = 0; r < 3; ++r) {
      gl[j][r * 4 + 0] = R[r * 3 + 0];
      gl[j][r * 4 + 1] = R[r * 3 + 1];
      gl[j][r * 4 + 2] = R[r * 3 + 2];
      gl[j][r * 4 + 3] = (j == 0) ? Jj[r] : Jj[r] - jl[par][r];
    }
  }
  __syncthreads();

  if (j < NJ) {
    int a[12];
    int n = 0, cur = j;
    while (cur != 0 && n < 12) { a[n++] = cur; cur = parent[cur - 1]; }
    float G[12];
#pragma unroll
    for (int r = 0; r < 3; ++r)
#pragma unroll
      for (int cc = 0; cc < 4; ++cc) G[r * 4 + cc] = gl[0][r * 4 + cc];
    for (int i = n - 1; i >= 0; --i) {
      const float* L = gl[a[i]];
      float C[12];
#pragma unroll
      for (int r = 0; r < 3; ++r) {
#pragma unroll
        for (int cc = 0; cc < 4; ++cc) {
          float sacc = (cc == 3) ? G[r * 4 + 3] : 0.f;
#pragma unroll
          for (int k = 0; k < 3; ++k) sacc += G[r * 4 + k] * L[k * 4 + cc];
          C[r * 4 + cc] = sacc;
        }
      }
#pragma unroll
      for (int k = 0; k < 12; ++k) G[k] = C[k];
    }
    float* A = Amat + b * 288 + j * 12;
#pragma unroll
    for (int r = 0; r < 3; ++r) {
      A[r * 4 + 0] = G[r * 4 + 0];
      A[r * 4 + 1] = G[r * 4 + 1];
      A[r * 4 + 2] = G[r * 4 + 2];
      A[r * 4 + 3] = G[r * 4 + 3] -
                     (G[r * 4 + 0] * jl[j][0] + G[r * 4 + 1] * jl[j][1] + G[r * 4 + 2] * jl[j][2]);
    }
  }
}

// ---------------- K2: B prep  Bbuf[n][k]: 0..206 posedirs, 207..216 shapedirs, rest 0 ----------------
__global__ void k_prepb(const float* __restrict__ pdirs, const float* __restrict__ sdirs,
                        ushort* __restrict__ Bbuf) {
  int idx = blockIdx.x * 256 + threadIdx.x;  // NCOLP*28
  int n = idx / 28, k8 = idx % 28;
  int kbase = k8 * 8;
  ushort8 o;
#pragma unroll
  for (int e = 0; e < 8; ++e) {
    int k = kbase + e;
    float v = 0.f;
    if (n < NCOL) {
      if (k < 207) v = pdirs[(size_t)n * 207 + k];
      else if (k < 217) v = sdirs[(size_t)n * 10 + (k - 207)];
    }
    o[e] = bf16_rne(v);
  }
  *(ushort8*)(Bbuf + (size_t)n * KK + kbase) = o;
}

// ---------------- K3: MFMA GEMM  out[b][n] = vtemp[n] + sum_k Abuf[b][k]*Bbuf[n][k] ----------------
__launch_bounds__(256)
__global__ void k_gemm(const ushort* __restrict__ Abuf, const ushort* __restrict__ Bbuf,
                       const float* __restrict__ vtemp, float* __restrict__ out) {
  int tid = threadIdx.x;
  int wid = tid >> 6, lane = tid & 63;
  int lo = lane & 15, hi = lane >> 4;
  int n0 = blockIdx.x * 128 + wid * 32;
  int m0b = blockIdx.y * 64;

  bf16x8 Bf[2][7];
#pragma unroll
  for (int s = 0; s < 2; ++s) {
    const ushort* brow = Bbuf + (size_t)(n0 + s * 16 + lo) * KK + hi * 8;
#pragma unroll
    for (int kc = 0; kc < 7; ++kc)
      Bf[s][kc] = *(const bf16x8*)(brow + kc * 32);
  }

  int col0 = n0 + lo;
  int col1 = n0 + 16 + lo;
  float vt0 = (col0 < NCOL) ? vtemp[col0] : 0.f;
  float vt1 = (col1 < NCOL) ? vtemp[col1] : 0.f;

#pragma unroll
  for (int mt = 0; mt < 4; ++mt) {
    int m0 = m0b + mt * 16;
    const ushort* arow = Abuf + (size_t)(m0 + lo) * KK + hi * 8;
    f32x4 acc0 = {vt0, vt0, vt0, vt0};
    f32x4 acc1 = {vt1, vt1, vt1, vt1};
#pragma unroll
    for (int kc = 0; kc < 7; ++kc) {
      bf16x8 Af = *(const bf16x8*)(arow + kc * 32);
      acc0 = __builtin_amdgcn_mfma_f32_16x16x32_bf16(Af, Bf[0][kc], acc0, 0, 0, 0);
      acc1 = __builtin_amdgcn_mfma_f32_16x16x32_bf16(Af, Bf[1][kc], acc1, 0, 0, 0);
    }
    if (col0 < NCOL) {
#pragma unroll
      for (int r = 0; r < 4; ++r)
        out[(size_t)(m0 + hi * 4 + r) * NCOL + col0] = acc0[r];
    }
    if (col1 < NCOL) {
#pragma unroll
      for (int r = 0; r < 4; ++r)
        out[(size_t)(m0 + hi * 4 + r) * NCOL + col1] = acc1[r];
    }
  }
}

// ---------------- K4: skinning in place on d_out (vp already in out) ----------------
__launch_bounds__(256)
__global__ void k_skin(const float* __restrict__ wgt, const float* __restrict__ Amat,
                       float* __restrict__ out) {
  __shared__ float Al[BT * 288];  // 18432 B
  __shared__ float wl[VT * 25];   // 6400 B

  int tid = threadIdx.x;
  int vt0 = blockIdx.x * VT, b0 = blockIdx.y * BT;
  int tv = tid & 63, bg = tid >> 6;
  int vg = vt0 + tv;
  bool vok = vg < NV;

  {
    const f4* srcA = (const f4*)(Amat + (size_t)b0 * 288);
    f4* dstA = (f4*)Al;
    for (int i = tid; i < BT * 72; i += 256) dstA[i] = srcA[i];
  }
  for (int i = tid; i < VT * 24; i += 256) {
    int v = i / 24, q = i % 24;
    wl[v * 25 + q] = (vt0 + v < NV) ? wgt[(size_t)(vt0 + v) * 24 + q] : 0.f;
  }
  __syncthreads();

  // read v_posed (written by k_gemm)
  float vp[4][3];
#pragma unroll
  for (int k = 0; k < 4; ++k) {
    int bl = b0 + bg * 4 + k;
    const float* ip = out + ((size_t)bl * NV + vg) * 3;
    vp[k][0] = vok ? ip[0] : 0.f;
    vp[k][1] = vok ? ip[1] : 0.f;
    vp[k][2] = vok ? ip[2] : 0.f;
  }

  // T[k] = sum_j w[v][j] * A[b][j]   (12 floats each)
  float T[4][12];
#pragma unroll
  for (int k = 0; k < 4; ++k)
#pragma unroll
    for (int q = 0; q < 12; ++q) T[k][q] = 0.f;

  const f4* A4 = (const f4*)Al;
  for (int j = 0; j < NJ; ++j) {
    float w = wl[tv * 25 + j];
#pragma unroll
    for (int k = 0; k < 4; ++k) {
      int bl = bg * 4 + k;
      f4 a0 = A4[bl * 72 + j * 3 + 0];
      f4 a1 = A4[bl * 72 + j * 3 + 1];
      f4 a2 = A4[bl * 72 + j * 3 + 2];
      T[k][0] += w * a0.x; T[k][1] += w * a0.y; T[k][2]  += w * a0.z; T[k][3]  += w * a0.w;
      T[k][4] += w * a1.x; T[k][5] += w * a1.y; T[k][6]  += w * a1.z; T[k][7]  += w * a1.w;
      T[k][8] += w * a2.x; T[k][9] += w * a2.y; T[k][10] += w * a2.z; T[k][11] += w * a2.w;
    }
  }

  if (vok) {
#pragma unroll
    for (int k = 0; k < 4; ++k) {
      int bl = b0 + bg * 4 + k;
      float* o = out + ((size_t)bl * NV + vg) * 3;
      o[0] = T[k][0] * vp[k][0] + T[k][1] * vp[k][1] + T[k][2]  * vp[k][2] + T[k][3];
      o[1] = T[k][4] * vp[k][0] + T[k][5] * vp[k][1] + T[k][6]  * vp[k][2] + T[k][7];
      o[2] = T[k][8] * vp[k][0] + T[k][9] * vp[k][1] + T[k][10] * vp[k][2] + T[k][11];
    }
  }
}

extern "C" void kernel_launch(void* const* d_in, const int* in_sizes, int n_in,
                              void* d_out, int out_size, void* d_ws, size_t ws_size,
                              hipStream_t stream) {
  const float* pose   = (const float*)d_in[0];
  const float* beta   = (const float*)d_in[1];
  const float* vtemp  = (const float*)d_in[2];
  const float* sdirs  = (const float*)d_in[3];
  const float* pdirs  = (const float*)d_in[4];
  const float* Jreg   = (const float*)d_in[5];
  const float* wgt    = (const float*)d_in[6];
  const int*   parent = (const int*)d_in[7];
  float* out = (float*)d_out;

  ushort* Abuf = (ushort*)d_ws;
  ushort* Bbuf = Abuf + (size_t)BATCH * KK;
  float*  Amat = (float*)(Bbuf + (size_t)NCOLP * KK);
  float*  JSp  = Amat + (size_t)BATCH * 288;
  float*  part = JSp + NJ * 33;

  hipLaunchKernelGGL(k_jregA, dim3(NJ, 8), dim3(256), 0, stream, Jreg, vtemp, sdirs, part);
  hipLaunchKernelGGL(k_jregB, dim3(4), dim3(256), 0, stream, part, JSp);
  hipLaunchKernelGGL(k_prepb, dim3((NCOLP * 28) / 256), dim3(256), 0, stream, pdirs, sdirs, Bbuf);
  hipLaunchKernelGGL(k_batch, dim3(BATCH), dim3(64), 0, stream, pose, beta, parent, JSp, Abuf, Amat);
  hipLaunchKernelGGL(k_gemm, dim3(NCOLP / 128, 8), dim3(256), 0, stream, Abuf, Bbuf, vtemp, out);
  dim3 grid((NV + VT - 1) / VT, BATCH / BT);
  hipLaunchKernelGGL(k_skin, grid, dim3(256), 0, stream, wgt, Amat, out);
}

// Round 4
// 104.357 us; speedup vs baseline: 5.3927x; 1.0755x over previous
//
#include <hip/hip_runtime.h>

#define NV 6890
#define NJ 24
#define BATCH 512
#define NCOL 20670   // NV*3
#define NCOLP 20736  // padded to 128
#define KK 224       // 207 pose + 10 beta + 7 zero
#define VT 64
#define BT 16
#define JCH 864      // vert chunk for jreg stage A (8*864 >= 6890)

typedef float f4 __attribute__((ext_vector_type(4)));
typedef float f32x4 __attribute__((ext_vector_type(4)));
typedef short bf16x8 __attribute__((ext_vector_type(8)));
typedef unsigned short ushort8 __attribute__((ext_vector_type(8)));

// ws layout (bytes):
//   Abuf  ushort[512][224]     @ 0
//   Bbuf  ushort[20736][224]   @ 229376
//   Amat  float[512][24][12]   @ 9519104
//   JSp   float[24][33]        @ 10108928
//   part  float[24][8][33]     @ 10112096

__device__ __forceinline__ ushort bf16_rne(float x) {
  union { float f; unsigned u; } c; c.f = x;
  unsigned r = c.u + 0x7fffu + ((c.u >> 16) & 1u);
  return (ushort)(r >> 16);
}

// ---------------- K0a: partial JS reduction, grid (24, 8) ----------------
__global__ void k_jregA(const float* __restrict__ Jreg, const float* __restrict__ vtemp,
                        const float* __restrict__ sdirs, float* __restrict__ partial) {
  int j = blockIdx.x, bz = blockIdx.y;
  int tid = threadIdx.x;
  float acc[33];
#pragma unroll
  for (int i = 0; i < 33; ++i) acc[i] = 0.f;
  int v0 = bz * JCH;
  int v1 = v0 + JCH; if (v1 > NV) v1 = NV;
  for (int v = v0 + tid; v < v1; v += 256) {
    float w = Jreg[(size_t)j * NV + v];
    const float* vt = vtemp + (size_t)v * 3;
    acc[0] += w * vt[0]; acc[1] += w * vt[1]; acc[2] += w * vt[2];
    const float* sdv = sdirs + (size_t)v * 30;
#pragma unroll
    for (int t = 0; t < 30; ++t) acc[3 + t] += w * sdv[t];
  }
  // wave butterfly reduce (all lanes end with the sum)
#pragma unroll
  for (int i = 0; i < 33; ++i) {
    float a = acc[i];
#pragma unroll
    for (int s = 32; s > 0; s >>= 1) a += __shfl_xor(a, s, 64);
    acc[i] = a;
  }
  __shared__ float red[4][34];
  int lane = tid & 63, wv = tid >> 6;
  if (lane == 0) {
#pragma unroll
    for (int i = 0; i < 33; ++i) red[wv][i] = acc[i];
  }
  __syncthreads();
  if (tid < 33) {
    float s = red[0][tid] + red[1][tid] + red[2][tid] + red[3][tid];
    partial[((size_t)j * 8 + bz) * 33 + tid] = s;
  }
}

// ---------------- K0b: sum the 8 partials ----------------
__global__ void k_jregB(const float* __restrict__ partial, float* __restrict__ JSp) {
  int i = blockIdx.x * 256 + threadIdx.x;
  if (i < NJ * 33) {
    int j = i / 33, q = i % 33;
    float s = 0.f;
#pragma unroll
    for (int bz = 0; bz < 8; ++bz) s += partial[((size_t)j * 8 + bz) * 33 + q];
    JSp[i] = s;
  }
}

// ---------------- K1: per-batch joints, rodrigues, chain, A matrices, Abuf ----------------
__global__ void k_batch(const float* __restrict__ pose, const float* __restrict__ beta,
                        const int* __restrict__ parent, const float* __restrict__ JSp,
                        ushort* __restrict__ Abuf, float* __restrict__ Amat) {
  int b = blockIdx.x;
  int j = threadIdx.x;  // 64 threads
  __shared__ float jl[NJ][3];
  __shared__ float gl[NJ][16];

  float bt[10];
#pragma unroll
  for (int t = 0; t < 10; ++t) bt[t] = beta[b * 10 + t];

  float R[9];
  float Jj[3] = {0.f, 0.f, 0.f};
  if (j < NJ) {
    const float* js = JSp + j * 33;
#pragma unroll
    for (int c = 0; c < 3; ++c) {
      float a = js[c];
#pragma unroll
      for (int t = 0; t < 10; ++t) a += js[3 + c * 10 + t] * bt[t];
      Jj[c] = a;
      jl[j][c] = a;
    }
    float rx = pose[b * 72 + j * 3 + 0];
    float ry = pose[b * 72 + j * 3 + 1];
    float rz = pose[b * 72 + j * 3 + 2];
    float theta = sqrtf(rx * rx + ry * ry + rz * rz) + 1e-8f;
    float inv = 1.f / theta;
    float ax = rx * inv, ay = ry * inv, az = rz * inv;
    float c = cosf(theta), s = sinf(theta), oc = 1.f - c;
    R[0] = c + oc * ax * ax;      R[1] = oc * ax * ay - s * az; R[2] = oc * ax * az + s * ay;
    R[3] = oc * ax * ay + s * az; R[4] = c + oc * ay * ay;      R[5] = oc * ay * az - s * ax;
    R[6] = oc * ax * az - s * ay; R[7] = oc * ay * az + s * ax; R[8] = c + oc * az * az;
  }
  __syncthreads();

  // Abuf cols: 0..206 lrotmin, 207..216 beta, 217..223 zero (bf16)
  if (j >= 1 && j < NJ) {
    ushort* lr = Abuf + b * KK + (j - 1) * 9;
#pragma unroll
    for (int k = 0; k < 9; ++k)
      lr[k] = bf16_rne(R[k] - ((k == 0 || k == 4 || k == 8) ? 1.f : 0.f));
  }
  if (j >= 32 && j < 42) Abuf[b * KK + 207 + (j - 32)] = bf16_rne(bt[j - 32]);
  if (j >= 42 && j < 49) Abuf[b * KK + 207 + (j - 32)] = 0;

  if (j < NJ) {
    int par = (j == 0) ? 0 : parent[j - 1];
#pragma unroll
    for (int r = 0; r < 3; ++r) {
      gl[j][r * 4 + 0] = R[r * 3 + 0];
      gl[j][r * 4 + 1] = R[r * 3 + 1];
      gl[j][r * 4 + 2] = R[r * 3 + 2];
      gl[j][r * 4 + 3] = (j == 0) ? Jj[r] : Jj[r] - jl[par][r];
    }
  }
  __syncthreads();

  if (j < NJ) {
    int a[12];
    int n = 0, cur = j;
    while (cur != 0 && n < 12) { a[n++] = cur; cur = parent[cur - 1]; }
    float G[12];
#pragma unroll
    for (int r = 0; r < 3; ++r)
#pragma unroll
      for (int cc = 0; cc < 4; ++cc) G[r * 4 + cc] = gl[0][r * 4 + cc];
    for (int i = n - 1; i >= 0; --i) {
      const float* L = gl[a[i]];
      float C[12];
#pragma unroll
      for (int r = 0; r < 3; ++r) {
#pragma unroll
        for (int cc = 0; cc < 4; ++cc) {
          float sacc = (cc == 3) ? G[r * 4 + 3] : 0.f;
#pragma unroll
          for (int k = 0; k < 3; ++k) sacc += G[r * 4 + k] * L[k * 4 + cc];
          C[r * 4 + cc] = sacc;
        }
      }
#pragma unroll
      for (int k = 0; k < 12; ++k) G[k] = C[k];
    }
    float* A = Amat + b * 288 + j * 12;
#pragma unroll
    for (int r = 0; r < 3; ++r) {
      A[r * 4 + 0] = G[r * 4 + 0];
      A[r * 4 + 1] = G[r * 4 + 1];
      A[r * 4 + 2] = G[r * 4 + 2];
      A[r * 4 + 3] = G[r * 4 + 3] -
                     (G[r * 4 + 0] * jl[j][0] + G[r * 4 + 1] * jl[j][1] + G[r * 4 + 2] * jl[j][2]);
    }
  }
}

// ---------------- K2: B prep  Bbuf[n][k]: 0..206 posedirs, 207..216 shapedirs, rest 0 ----------------
__global__ void k_prepb(const float* __restrict__ pdirs, const float* __restrict__ sdirs,
                        ushort* __restrict__ Bbuf) {
  int idx = blockIdx.x * 256 + threadIdx.x;  // NCOLP*28
  int n = idx / 28, k8 = idx % 28;
  int kbase = k8 * 8;
  ushort8 o;
#pragma unroll
  for (int e = 0; e < 8; ++e) {
    int k = kbase + e;
    float v = 0.f;
    if (n < NCOL) {
      if (k < 207) v = pdirs[(size_t)n * 207 + k];
      else if (k < 217) v = sdirs[(size_t)n * 10 + (k - 207)];
    }
    o[e] = bf16_rne(v);
  }
  *(ushort8*)(Bbuf + (size_t)n * KK + kbase) = o;
}

// ---------------- K3: MFMA GEMM  out[b][n] = vtemp[n] + sum_k Abuf[b][k]*Bbuf[n][k] ----------------
__launch_bounds__(256)
__global__ void k_gemm(const ushort* __restrict__ Abuf, const ushort* __restrict__ Bbuf,
                       const float* __restrict__ vtemp, float* __restrict__ out) {
  int tid = threadIdx.x;
  int wid = tid >> 6, lane = tid & 63;
  int lo = lane & 15, hi = lane >> 4;
  int n0 = blockIdx.x * 128 + wid * 32;
  int m0b = blockIdx.y * 64;

  bf16x8 Bf[2][7];
#pragma unroll
  for (int s = 0; s < 2; ++s) {
    const ushort* brow = Bbuf + (size_t)(n0 + s * 16 + lo) * KK + hi * 8;
#pragma unroll
    for (int kc = 0; kc < 7; ++kc)
      Bf[s][kc] = *(const bf16x8*)(brow + kc * 32);
  }

  int col0 = n0 + lo;
  int col1 = n0 + 16 + lo;
  float vt0 = (col0 < NCOL) ? vtemp[col0] : 0.f;
  float vt1 = (col1 < NCOL) ? vtemp[col1] : 0.f;

#pragma unroll
  for (int mt = 0; mt < 4; ++mt) {
    int m0 = m0b + mt * 16;
    const ushort* arow = Abuf + (size_t)(m0 + lo) * KK + hi * 8;
    f32x4 acc0 = {vt0, vt0, vt0, vt0};
    f32x4 acc1 = {vt1, vt1, vt1, vt1};
#pragma unroll
    for (int kc = 0; kc < 7; ++kc) {
      bf16x8 Af = *(const bf16x8*)(arow + kc * 32);
      acc0 = __builtin_amdgcn_mfma_f32_16x16x32_bf16(Af, Bf[0][kc], acc0, 0, 0, 0);
      acc1 = __builtin_amdgcn_mfma_f32_16x16x32_bf16(Af, Bf[1][kc], acc1, 0, 0, 0);
    }
    if (col0 < NCOL) {
#pragma unroll
      for (int r = 0; r < 4; ++r)
        out[(size_t)(m0 + hi * 4 + r) * NCOL + col0] = acc0[r];
    }
    if (col1 < NCOL) {
#pragma unroll
      for (int r = 0; r < 4; ++r)
        out[(size_t)(m0 + hi * 4 + r) * NCOL + col1] = acc1[r];
    }
  }
}

// ---------------- K4: skinning in place on d_out; A via wave-uniform scalar loads ----------------
__launch_bounds__(256)
__global__ void k_skin(const float* __restrict__ wgt, const float* __restrict__ Amat,
                       float* __restrict__ out) {
  int tid = threadIdx.x;
  int vt0 = blockIdx.x * VT, b0 = blockIdx.y * BT;
  int tv = tid & 63;
  // wave-uniform batch-group index -> scalar pipe for all A loads
  int bg = __builtin_amdgcn_readfirstlane(tid >> 6);
  int vg = vt0 + tv;
  bool vok = vg < NV;

  // per-thread weights (24 floats, float4 loads)
  float w[24];
  if (vok) {
    const f4* wp = (const f4*)(wgt + (size_t)vg * 24);
#pragma unroll
    for (int q = 0; q < 6; ++q) {
      f4 t = wp[q];
      w[q * 4 + 0] = t.x; w[q * 4 + 1] = t.y; w[q * 4 + 2] = t.z; w[q * 4 + 3] = t.w;
    }
  } else {
#pragma unroll
    for (int q = 0; q < 24; ++q) w[q] = 0.f;
  }

  // read v_posed (written by k_gemm)
  float vp[4][3];
#pragma unroll
  for (int k = 0; k < 4; ++k) {
    int bl = b0 + bg * 4 + k;
    const float* ip = out + ((size_t)bl * NV + vg) * 3;
    vp[k][0] = vok ? ip[0] : 0.f;
    vp[k][1] = vok ? ip[1] : 0.f;
    vp[k][2] = vok ? ip[2] : 0.f;
  }

  // T[k] = sum_j w[j] * A[b0+bg*4+k][j]  — A loads are wave-uniform (SGPR)
  const float* Abase = Amat + (size_t)(b0 + bg * 4) * 288;
  float T[4][12];
#pragma unroll
  for (int k = 0; k < 4; ++k)
#pragma unroll
    for (int q = 0; q < 12; ++q) T[k][q] = 0.f;

  for (int j = 0; j < NJ; ++j) {
    float wv = w[j];
#pragma unroll
    for (int k = 0; k < 4; ++k) {
      const float* Ak = Abase + k * 288 + j * 12;
#pragma unroll
      for (int q = 0; q < 12; ++q) T[k][q] += wv * Ak[q];
    }
  }

  if (vok) {
#pragma unroll
    for (int k = 0; k < 4; ++k) {
      int bl = b0 + bg * 4 + k;
      float* o = out + ((size_t)bl * NV + vg) * 3;
      o[0] = T[k][0] * vp[k][0] + T[k][1] * vp[k][1] + T[k][2]  * vp[k][2] + T[k][3];
      o[1] = T[k][4] * vp[k][0] + T[k][5] * vp[k][1] + T[k][6]  * vp[k][2] + T[k][7];
      o[2] = T[k][8] * vp[k][0] + T[k][9] * vp[k][1] + T[k][10] * vp[k][2] + T[k][11];
    }
  }
}

extern "C" void kernel_launch(void* const* d_in, const int* in_sizes, int n_in,
                              void* d_out, int out_size, void* d_ws, size_t ws_size,
                              hipStream_t stream) {
  const float* pose   = (const float*)d_in[0];
  const float* beta   = (const float*)d_in[1];
  const float* vtemp  = (const float*)d_in[2];
  const float* sdirs  = (const float*)d_in[3];
  const float* pdirs  = (const float*)d_in[4];
  const float* Jreg   = (const float*)d_in[5];
  const float* wgt    = (const float*)d_in[6];
  const int*   parent = (const int*)d_in[7];
  float* out = (float*)d_out;

  ushort* Abuf = (ushort*)d_ws;
  ushort* Bbuf = Abuf + (size_t)BATCH * KK;
  float*  Amat = (float*)(Bbuf + (size_t)NCOLP * KK);
  float*  JSp  = Amat + (size_t)BATCH * 288;
  float*  part = JSp + NJ * 33;

  hipLaunchKernelGGL(k_jregA, dim3(NJ, 8), dim3(256), 0, stream, Jreg, vtemp, sdirs, part);
  hipLaunchKernelGGL(k_jregB, dim3(4), dim3(256), 0, stream, part, JSp);
  hipLaunchKernelGGL(k_prepb, dim3((NCOLP * 28) / 256), dim3(256), 0, stream, pdirs, sdirs, Bbuf);
  hipLaunchKernelGGL(k_batch, dim3(BATCH), dim3(64), 0, stream, pose, beta, parent, JSp, Abuf, Amat);
  hipLaunchKernelGGL(k_gemm, dim3(NCOLP / 128, 8), dim3(256), 0, stream, Abuf, Bbuf, vtemp, out);
  dim3 grid((NV + VT - 1) / VT, BATCH / BT);
  hipLaunchKernelGGL(k_skin, grid, dim3(256), 0, stream, wgt, Amat, out);
}